// Round 6
// baseline (313.349 us; speedup 1.0000x reference)
//
#include <hip/hip_runtime.h>
#include <math.h>

// Problem constants (fixed by the reference setup)
constexpr int Nn = 131072;   // rows
constexpr int Dd = 256;      // feature dim
constexpr int Pp = 64;       // proj dim
constexpr int Gg = 8192;     // groups
constexpr int Ee = 260096;   // edges
constexpr float SIM_TH = 0.5f;

typedef _Float16 half8 __attribute__((ext_vector_type(8)));
typedef _Float16 half4 __attribute__((ext_vector_type(4)));
typedef float floatx4 __attribute__((ext_vector_type(4)));

// ---------------------------------------------------------------------------
// K0: per-group member count (131K atomics over 8192 counters) + W swizzle.
// First 16384 threads pre-swizzle W [256][64] fp32 into MFMA B-frag order
// fp16: lane l, elem j of frag (c,t) holds B[c*32+(l>>4)*8+j][t*16+(l&15)];
// flat Wf[((c*4+t)*64+l)*8+j].  32 KB, L1/L2-resident.
// ---------------------------------------------------------------------------
__global__ __launch_bounds__(256) void k_count_wfrag(
    const int* __restrict__ gid, int* __restrict__ cnt,
    const float* __restrict__ W, _Float16* __restrict__ Wf)
{
    const int i = blockIdx.x * 256 + threadIdx.x;
    atomicAdd(&cnt[gid[i]], 1);
    if (i < 16384) {
        const int j = i & 7;
        const int l = (i >> 3) & 63;
        const int t = (i >> 9) & 3;
        const int c = i >> 11;
        const int k = c * 32 + (l >> 4) * 8 + j;
        const int n = t * 16 + (l & 15);
        Wf[i] = (_Float16)W[k * Pp + n];
    }
}

// ---------------------------------------------------------------------------
// K1: single-block exclusive prefix scan over the 8192 group counts.
// ---------------------------------------------------------------------------
__global__ __launch_bounds__(256) void k_scan(
    const int* __restrict__ cnt,
    int* __restrict__ offsets,
    int* __restrict__ cursor)
{
    __shared__ int lds[256];
    const int t = threadIdx.x;
    const int base = t * 32;

    int s = 0;
#pragma unroll
    for (int j = 0; j < 32; ++j) s += cnt[base + j];
    lds[t] = s;
    __syncthreads();

    int v = s;
    for (int off = 1; off < 256; off <<= 1) {
        int add = (t >= off) ? lds[t - off] : 0;
        __syncthreads();
        v += add;
        lds[t] = v;
        __syncthreads();
    }

    int run = v - s;
    for (int j = 0; j < 32; ++j) {
        offsets[base + j] = run;
        cursor[base + j]  = run;
        run += cnt[base + j];
    }
}

// ---------------------------------------------------------------------------
// K2: scatter row indices into group buckets (counting sort, phase 2).
// ---------------------------------------------------------------------------
__global__ __launch_bounds__(256) void k_scatter_idx(
    const int* __restrict__ gid,
    int* __restrict__ cursor,
    int* __restrict__ bucket)
{
    const int i = blockIdx.x * 256 + threadIdx.x;
    const int p = atomicAdd(&cursor[gid[i]], 1);
    bucket[p] = i;
}

// ---------------------------------------------------------------------------
// K3: FUSED projection + group mean. One wave per group (4 groups/block).
// Per 16-row tile of the group's (sorted) rows:
//   - each row loaded ONCE wave-wide (lane = col float4, coalesced 1 KB),
//   - accumulated into group-sum (1 float4/lane),
//   - cvt fp16 -> wave-private LDS tile [16][264] (pad 264: conflict-free
//     b128 frag reads; wave-synchronous, NO __syncthreads needed),
//   - MFMA 16x16x32_f16 over 8 K-chunks x 4 n-tiles; B-frags from 32 KB Wf.
// Epilogue per tile: proj rows (fp16, predicated scatter). End: mean write
// (coalesced 1 KB per group). features thus read from HBM exactly once.
// ---------------------------------------------------------------------------
__global__ __launch_bounds__(256) void k_fused(
    const float* __restrict__ A,          // features [N][256]
    const _Float16* __restrict__ Wf,      // swizzled B-frags
    const int* __restrict__ bucket,       // [N] sorted-by-group row ids
    const int* __restrict__ offsets,      // [G]
    const int* __restrict__ cnt,          // [G]
    _Float16* __restrict__ proj,          // [N][64] fp16
    float* __restrict__ out_means)        // [G][256]
{
    __shared__ _Float16 lds[4][16][264];  // 33 KB/block, per-wave tiles

    const int l  = threadIdx.x & 63;
    const int w  = threadIdx.x >> 6;
    const int am = l & 15;                // frag row within tile
    const int q  = l >> 4;                // quad 0..3
    const int g  = blockIdx.x * 4 + w;

    const int n     = cnt[g];
    const int start = offsets[g];
    const half8* __restrict__ bfrag = reinterpret_cast<const half8*>(Wf) + l;

    float4 msum = make_float4(0.f, 0.f, 0.f, 0.f);

    const int T = (n + 15) >> 4;
    for (int t = 0; t < T; ++t) {
        // ---- stage 16 rows: load once, sum, cvt to LDS (zeros for pads) ----
#pragma unroll 4
        for (int j = 0; j < 16; ++j) {
            const int rj = t * 16 + j;
            const bool v = rj < n;
            const int row = bucket[start + (v ? rj : 0)];
            float4 f = make_float4(0.f, 0.f, 0.f, 0.f);
            if (v) f = *reinterpret_cast<const float4*>(A + (size_t)row * Dd + l * 4);
            msum.x += f.x; msum.y += f.y; msum.z += f.z; msum.w += f.w;
            half4 h;
            h[0] = (_Float16)f.x; h[1] = (_Float16)f.y;
            h[2] = (_Float16)f.z; h[3] = (_Float16)f.w;
            *reinterpret_cast<half4*>(&lds[w][j][l * 4]) = h;
        }

        // ---- MFMA: 16 rows x 64 cols, K=256 ----
        floatx4 acc[4];
#pragma unroll
        for (int tt = 0; tt < 4; ++tt) acc[tt] = (floatx4){0.f, 0.f, 0.f, 0.f};

#pragma unroll
        for (int c = 0; c < 8; ++c) {
            const half8 a = *reinterpret_cast<const half8*>(&lds[w][am][c * 32 + q * 8]);
            const half8 b0 = bfrag[(c * 4 + 0) * 64];
            const half8 b1 = bfrag[(c * 4 + 1) * 64];
            const half8 b2 = bfrag[(c * 4 + 2) * 64];
            const half8 b3 = bfrag[(c * 4 + 3) * 64];
            acc[0] = __builtin_amdgcn_mfma_f32_16x16x32_f16(a, b0, acc[0], 0, 0, 0);
            acc[1] = __builtin_amdgcn_mfma_f32_16x16x32_f16(a, b1, acc[1], 0, 0, 0);
            acc[2] = __builtin_amdgcn_mfma_f32_16x16x32_f16(a, b2, acc[2], 0, 0, 0);
            acc[3] = __builtin_amdgcn_mfma_f32_16x16x32_f16(a, b3, acc[3], 0, 0, 0);
        }

        // ---- proj epilogue: D row = q*4 + r -> global row bucket[...] ----
#pragma unroll
        for (int r = 0; r < 4; ++r) {
            const int rr = t * 16 + q * 4 + r;
            if (rr < n) {
                const int prow = bucket[start + rr];
                _Float16* pp = proj + (size_t)prow * Pp + (l & 15);
#pragma unroll
                for (int tt = 0; tt < 4; ++tt)
                    pp[tt * 16] = (_Float16)acc[tt][r];
            }
        }
    }

    // ---- mean write: coalesced 1 KB per group ----
    const float inv = 1.0f / (float)max(n, 1);
    msum.x *= inv; msum.y *= inv; msum.z *= inv; msum.w *= inv;
    *reinterpret_cast<float4*>(out_means + (size_t)g * Dd + l * 4) = msum;
}

// ---------------------------------------------------------------------------
// K4: edges over fp16 proj — 8 lanes per edge (half8 = 8 cols each),
// 4 edges per subgroup -> 8 independent 16 B loads in flight per lane,
// 3-step shuffle reduce, sigmoid. proj footprint 16 MB (L2/L3-resident).
// ---------------------------------------------------------------------------
__global__ __launch_bounds__(256) void k_edges(
    const _Float16* __restrict__ proj,    // [N][64] fp16
    const int*      __restrict__ ei,      // [2][E]
    float* __restrict__ out_logits)       // [E]
{
    const int sub = threadIdx.x & 7;                       // lane within edge
    const int sg  = blockIdx.x * 32 + (threadIdx.x >> 3);  // subgroup id
    const int e0  = sg * 4;

    int s[4], t[4];
#pragma unroll
    for (int u = 0; u < 4; ++u) { s[u] = ei[e0 + u]; t[u] = ei[Ee + e0 + u]; }

    half8 a[4], b[4];
#pragma unroll
    for (int u = 0; u < 4; ++u) {
        a[u] = *reinterpret_cast<const half8*>(proj + (size_t)s[u] * Pp + sub * 8);
        b[u] = *reinterpret_cast<const half8*>(proj + (size_t)t[u] * Pp + sub * 8);
    }

    float v[4];
#pragma unroll
    for (int u = 0; u < 4; ++u) {
        float acc = 0.f;
#pragma unroll
        for (int j = 0; j < 8; ++j)
            acc = fmaf((float)a[u][j], (float)b[u][j], acc);
        v[u] = acc;
    }

#pragma unroll
    for (int off = 4; off >= 1; off >>= 1) {
#pragma unroll
        for (int u = 0; u < 4; ++u) v[u] += __shfl_xor(v[u], off, 64);
    }

    if (sub < 4) {
        const float x = v[sub];
        out_logits[e0 + sub] = 1.0f / (1.0f + __expf(-(x - SIM_TH)));
    }
}

// ---------------------------------------------------------------------------
extern "C" void kernel_launch(void* const* d_in, const int* in_sizes, int n_in,
                              void* d_out, int out_size, void* d_ws, size_t ws_size,
                              hipStream_t stream)
{
    const float* features = (const float*)d_in[0];
    const float* W        = (const float*)d_in[1];
    const int*   ei       = (const int*)d_in[2];
    const int*   gid      = (const int*)d_in[3];
    // d_in[4] = num_groups scalar (fixed at 8192, hardcoded)

    float* out_means  = (float*)d_out;                    // [G*D]
    float* out_logits = out_means + (size_t)Gg * Dd;      // [E]

    _Float16*  proj    = (_Float16*)d_ws;                 // N*P f16 (16 MB)
    int*       bucket  = (int*)(proj + (size_t)Nn * Pp);  // [N]
    int*       cnt     = bucket + Nn;                     // [G]
    int*       offsets = cnt + Gg;                        // [G]
    int*       cursor  = offsets + Gg;                    // [G]
    _Float16*  Wf      = (_Float16*)(cursor + Gg);        // 16384 f16 (32 KB)

    hipMemsetAsync(cnt, 0, (size_t)Gg * sizeof(int), stream);

    hipLaunchKernelGGL(k_count_wfrag, dim3(Nn / 256), dim3(256), 0, stream,
                       gid, cnt, W, Wf);
    hipLaunchKernelGGL(k_scan, dim3(1), dim3(256), 0, stream,
                       cnt, offsets, cursor);
    hipLaunchKernelGGL(k_scatter_idx, dim3(Nn / 256), dim3(256), 0, stream,
                       gid, cursor, bucket);
    hipLaunchKernelGGL(k_fused, dim3(Gg / 4), dim3(256), 0, stream,
                       features, Wf, bucket, offsets, cnt, proj, out_means);
    hipLaunchKernelGGL(k_edges, dim3(Ee / 128), dim3(256), 0, stream,
                       proj, ei, out_logits);
}

// Round 7
// 252.068 us; speedup vs baseline: 1.2431x; 1.2431x over previous
//
#include <hip/hip_runtime.h>
#include <math.h>

// Problem constants (fixed by the reference setup)
constexpr int Nn = 131072;   // rows
constexpr int Dd = 256;      // feature dim
constexpr int Pp = 64;       // proj dim
constexpr int Gg = 8192;     // groups
constexpr int Ee = 260096;   // edges
constexpr float SIM_TH = 0.5f;

typedef _Float16 half8 __attribute__((ext_vector_type(8)));
typedef float floatx4 __attribute__((ext_vector_type(4)));

// ---------------------------------------------------------------------------
// K0: per-group member count (131K atomics over 8192 counters) + W swizzle.
// First 16384 threads pre-swizzle W [256][64] fp32 into MFMA B-frag order
// fp16: lane l, elem j of frag (c,t) holds B[c*32+(l>>4)*8+j][t*16+(l&15)];
// flat Wf[((c*4+t)*64+l)*8+j].  32 KB, L1/L2-resident.
// ---------------------------------------------------------------------------
__global__ __launch_bounds__(256) void k_count_wfrag(
    const int* __restrict__ gid, int* __restrict__ cnt,
    const float* __restrict__ W, _Float16* __restrict__ Wf)
{
    const int i = blockIdx.x * 256 + threadIdx.x;
    atomicAdd(&cnt[gid[i]], 1);
    if (i < 16384) {
        const int j = i & 7;
        const int l = (i >> 3) & 63;
        const int t = (i >> 9) & 3;
        const int c = i >> 11;
        const int k = c * 32 + (l >> 4) * 8 + j;
        const int n = t * 16 + (l & 15);
        Wf[i] = (_Float16)W[k * Pp + n];
    }
}

// ---------------------------------------------------------------------------
// K1: single-block exclusive prefix scan over the 8192 group counts.
// ---------------------------------------------------------------------------
__global__ __launch_bounds__(256) void k_scan(
    const int* __restrict__ cnt,
    int* __restrict__ offsets,
    int* __restrict__ cursor)
{
    __shared__ int lds[256];
    const int t = threadIdx.x;
    const int base = t * 32;

    int s = 0;
#pragma unroll
    for (int j = 0; j < 32; ++j) s += cnt[base + j];
    lds[t] = s;
    __syncthreads();

    int v = s;
    for (int off = 1; off < 256; off <<= 1) {
        int add = (t >= off) ? lds[t - off] : 0;
        __syncthreads();
        v += add;
        lds[t] = v;
        __syncthreads();
    }

    int run = v - s;
    for (int j = 0; j < 32; ++j) {
        offsets[base + j] = run;
        cursor[base + j]  = run;
        run += cnt[base + j];
    }
}

// ---------------------------------------------------------------------------
// K2 (merged): blocks [0,512): counting-sort scatter of row ids into buckets;
// blocks [512, 512+2048): fp16 MFMA projection (LDS-free, barrier-free),
// proj stored fp16. The tiny scatter hides under proj's HBM streaming.
// proj: wave w computes rows [blk*64 + w*16, +16) x 64 cols; K in 8 chunks
// of 32 via v_mfma_f32_16x16x32_f16; A-frags straight from global (cvt
// inline); B-frags coalesced b128 loads from 32 KB L1/L2-resident Wf.
// ---------------------------------------------------------------------------
__global__ __launch_bounds__(256) void k_mid(
    const float* __restrict__ A,          // features [N][256]
    const _Float16* __restrict__ Wf,      // swizzled B-frags
    _Float16* __restrict__ proj,          // [N][64] fp16
    const int* __restrict__ gid,          // [N]
    int* __restrict__ cursor,             // [G]
    int* __restrict__ bucket)             // [N]
{
    if (blockIdx.x < 512) {
        const int i = blockIdx.x * 256 + threadIdx.x;
        const int p = atomicAdd(&cursor[gid[i]], 1);
        bucket[p] = i;
        return;
    }
    const int blk = blockIdx.x - 512;

    const int l = threadIdx.x & 63;
    const int w = threadIdx.x >> 6;
    const int rowbase = blk * 64 + w * 16;
    const int am = l & 15;                // A-frag row within tile
    const int q  = l >> 4;                // quad 0..3

    const float* __restrict__ arow = A + (size_t)(rowbase + am) * Dd + q * 8;
    const half8* __restrict__ bfrag = reinterpret_cast<const half8*>(Wf) + l;

    floatx4 acc[4];
#pragma unroll
    for (int t = 0; t < 4; ++t) acc[t] = (floatx4){0.f, 0.f, 0.f, 0.f};

#pragma unroll
    for (int c = 0; c < 8; ++c) {
        const float4 fa = *reinterpret_cast<const float4*>(arow + c * 32);
        const float4 fb = *reinterpret_cast<const float4*>(arow + c * 32 + 4);
        half8 a;
        a[0] = (_Float16)fa.x; a[1] = (_Float16)fa.y;
        a[2] = (_Float16)fa.z; a[3] = (_Float16)fa.w;
        a[4] = (_Float16)fb.x; a[5] = (_Float16)fb.y;
        a[6] = (_Float16)fb.z; a[7] = (_Float16)fb.w;
        const half8 b0 = bfrag[(c * 4 + 0) * 64];
        const half8 b1 = bfrag[(c * 4 + 1) * 64];
        const half8 b2 = bfrag[(c * 4 + 2) * 64];
        const half8 b3 = bfrag[(c * 4 + 3) * 64];
        acc[0] = __builtin_amdgcn_mfma_f32_16x16x32_f16(a, b0, acc[0], 0, 0, 0);
        acc[1] = __builtin_amdgcn_mfma_f32_16x16x32_f16(a, b1, acc[1], 0, 0, 0);
        acc[2] = __builtin_amdgcn_mfma_f32_16x16x32_f16(a, b2, acc[2], 0, 0, 0);
        acc[3] = __builtin_amdgcn_mfma_f32_16x16x32_f16(a, b3, acc[3], 0, 0, 0);
    }

    // C/D layout: col = l&15, row = q*4 + reg  (m89-verified mapping)
#pragma unroll
    for (int t = 0; t < 4; ++t) {
#pragma unroll
        for (int r = 0; r < 4; ++r) {
            proj[(size_t)(rowbase + q * 4 + r) * Pp + t * 16 + am] =
                (_Float16)acc[t][r];
        }
    }
}

// ---------------------------------------------------------------------------
// K3 (merged): blocks [0,2048): group means (one wave per group, lane =
// float4 column slice, 8-deep unrolled gathers of L3-warm 1 KB rows);
// blocks [2048, 2048+2032): edge logits over fp16 proj (8 lanes/edge,
// 4 edges/subgroup -> 8 independent 16 B loads in flight, 3-step shuffle).
// BW-bound and latency-bound halves co-schedule and fill each other's stalls.
// ---------------------------------------------------------------------------
__global__ __launch_bounds__(256) void k_tail(
    const float* __restrict__ features,   // [N][256]
    const int* __restrict__ bucket,       // [N]
    const int* __restrict__ offsets,      // [G]
    const int* __restrict__ cnt,          // [G]
    float* __restrict__ out_means,        // [G][256]
    const _Float16* __restrict__ proj,    // [N][64] fp16
    const int* __restrict__ ei,           // [2][E]
    float* __restrict__ out_logits)       // [E]
{
    if (blockIdx.x < 2048) {
        const int lane = threadIdx.x & 63;
        const int g = blockIdx.x * 4 + (threadIdx.x >> 6);
        const int n = cnt[g];
        const int start = offsets[g];
        const int col = lane * 4;

        float4 s = make_float4(0.f, 0.f, 0.f, 0.f);
        int k = 0;
        for (; k + 8 <= n; k += 8) {
            int r[8];
#pragma unroll
            for (int u = 0; u < 8; ++u) r[u] = bucket[start + k + u];
            float4 f[8];
#pragma unroll
            for (int u = 0; u < 8; ++u)
                f[u] = *reinterpret_cast<const float4*>(features + (size_t)r[u] * Dd + col);
#pragma unroll
            for (int u = 0; u < 8; ++u) {
                s.x += f[u].x; s.y += f[u].y; s.z += f[u].z; s.w += f[u].w;
            }
        }
        for (; k < n; ++k) {
            const int r = bucket[start + k];
            const float4 f = *reinterpret_cast<const float4*>(features + (size_t)r * Dd + col);
            s.x += f.x; s.y += f.y; s.z += f.z; s.w += f.w;
        }
        const float inv = 1.0f / (float)max(n, 1);
        s.x *= inv; s.y *= inv; s.z *= inv; s.w *= inv;
        *reinterpret_cast<float4*>(out_means + (size_t)g * Dd + col) = s;
        return;
    }

    const int bid = blockIdx.x - 2048;
    const int sub = threadIdx.x & 7;                   // lane within edge
    const int sg  = bid * 32 + (threadIdx.x >> 3);     // subgroup id
    const int e0  = sg * 4;

    int s[4], t[4];
#pragma unroll
    for (int u = 0; u < 4; ++u) { s[u] = ei[e0 + u]; t[u] = ei[Ee + e0 + u]; }

    half8 a[4], b[4];
#pragma unroll
    for (int u = 0; u < 4; ++u) {
        a[u] = *reinterpret_cast<const half8*>(proj + (size_t)s[u] * Pp + sub * 8);
        b[u] = *reinterpret_cast<const half8*>(proj + (size_t)t[u] * Pp + sub * 8);
    }

    float v[4];
#pragma unroll
    for (int u = 0; u < 4; ++u) {
        float acc = 0.f;
#pragma unroll
        for (int j = 0; j < 8; ++j)
            acc = fmaf((float)a[u][j], (float)b[u][j], acc);
        v[u] = acc;
    }

#pragma unroll
    for (int off = 4; off >= 1; off >>= 1) {
#pragma unroll
        for (int u = 0; u < 4; ++u) v[u] += __shfl_xor(v[u], off, 64);
    }

    if (sub < 4) {
        const float x = v[sub];
        out_logits[e0 + sub] = 1.0f / (1.0f + __expf(-(x - SIM_TH)));
    }
}

// ---------------------------------------------------------------------------
extern "C" void kernel_launch(void* const* d_in, const int* in_sizes, int n_in,
                              void* d_out, int out_size, void* d_ws, size_t ws_size,
                              hipStream_t stream)
{
    const float* features = (const float*)d_in[0];
    const float* W        = (const float*)d_in[1];
    const int*   ei       = (const int*)d_in[2];
    const int*   gid      = (const int*)d_in[3];
    // d_in[4] = num_groups scalar (fixed at 8192, hardcoded)

    float* out_means  = (float*)d_out;                    // [G*D]
    float* out_logits = out_means + (size_t)Gg * Dd;      // [E]

    _Float16*  proj    = (_Float16*)d_ws;                 // N*P f16 (16 MB)
    int*       bucket  = (int*)(proj + (size_t)Nn * Pp);  // [N]
    int*       cnt     = bucket + Nn;                     // [G]
    int*       offsets = cnt + Gg;                        // [G]
    int*       cursor  = offsets + Gg;                    // [G]
    _Float16*  Wf      = (_Float16*)(cursor + Gg);        // 16384 f16 (32 KB)

    hipMemsetAsync(cnt, 0, (size_t)Gg * sizeof(int), stream);

    hipLaunchKernelGGL(k_count_wfrag, dim3(Nn / 256), dim3(256), 0, stream,
                       gid, cnt, W, Wf);
    hipLaunchKernelGGL(k_scan, dim3(1), dim3(256), 0, stream,
                       cnt, offsets, cursor);
    hipLaunchKernelGGL(k_mid, dim3(512 + Nn / 64), dim3(256), 0, stream,
                       features, Wf, proj, gid, cursor, bucket);
    hipLaunchKernelGGL(k_tail, dim3(2048 + Ee / 128), dim3(256), 0, stream,
                       features, bucket, offsets, cnt, out_means,
                       proj, ei, out_logits);
}

// Round 8
// 248.025 us; speedup vs baseline: 1.2634x; 1.0163x over previous
//
#include <hip/hip_runtime.h>
#include <math.h>

// Problem constants (fixed by the reference setup)
constexpr int Nn = 131072;   // rows
constexpr int Dd = 256;      // feature dim
constexpr int Pp = 64;       // proj dim
constexpr int Gg = 8192;     // groups
constexpr int Ee = 260096;   // edges
constexpr float SIM_TH = 0.5f;

typedef _Float16 half8 __attribute__((ext_vector_type(8)));
typedef float floatx4 __attribute__((ext_vector_type(4)));

// ---------------------------------------------------------------------------
// K0: per-group member count (131K atomics over 8192 counters) + W swizzle.
// First 16384 threads pre-swizzle W [256][64] fp32 into MFMA B-frag order
// fp16: lane l, elem j of frag (c,t) holds B[c*32+(l>>4)*8+j][t*16+(l&15)];
// flat Wf[((c*4+t)*64+l)*8+j].  32 KB.
// ---------------------------------------------------------------------------
__global__ __launch_bounds__(256) void k_count_wfrag(
    const int* __restrict__ gid, int* __restrict__ cnt,
    const float* __restrict__ W, _Float16* __restrict__ Wf)
{
    const int i = blockIdx.x * 256 + threadIdx.x;
    atomicAdd(&cnt[gid[i]], 1);
    if (i < 16384) {
        const int j = i & 7;
        const int l = (i >> 3) & 63;
        const int t = (i >> 9) & 3;
        const int c = i >> 11;
        const int k = c * 32 + (l >> 4) * 8 + j;
        const int n = t * 16 + (l & 15);
        Wf[i] = (_Float16)W[k * Pp + n];
    }
}

// ---------------------------------------------------------------------------
// K1: single-block exclusive prefix scan over the 8192 group counts.
// ---------------------------------------------------------------------------
__global__ __launch_bounds__(256) void k_scan(
    const int* __restrict__ cnt,
    int* __restrict__ offsets,
    int* __restrict__ cursor)
{
    __shared__ int lds[256];
    const int t = threadIdx.x;
    const int base = t * 32;

    int s = 0;
#pragma unroll
    for (int j = 0; j < 32; ++j) s += cnt[base + j];
    lds[t] = s;
    __syncthreads();

    int v = s;
    for (int off = 1; off < 256; off <<= 1) {
        int add = (t >= off) ? lds[t - off] : 0;
        __syncthreads();
        v += add;
        lds[t] = v;
        __syncthreads();
    }

    int run = v - s;
    for (int j = 0; j < 32; ++j) {
        offsets[base + j] = run;
        cursor[base + j]  = run;
        run += cnt[base + j];
    }
}

// ---------------------------------------------------------------------------
// K2 (merged): blocks [0,512): counting-sort scatter of row ids into buckets;
// blocks [512, 512+2048): fp16 MFMA projection. Wf is staged into LDS once
// per block (32 KB, one barrier) so B-frags come from conflict-free
// ds_read_b128 (~12 cyc) instead of L1-thrashed global loads (~200 cyc).
// Wave w: rows [blk*64 + w*16, +16) x 64 cols; K in 8 chunks of 32 via
// v_mfma_f32_16x16x32_f16; A-frags straight from global, cvt fp16 inline.
// ---------------------------------------------------------------------------
__global__ __launch_bounds__(256) void k_mid(
    const float* __restrict__ A,          // features [N][256]
    const _Float16* __restrict__ Wf,      // swizzled B-frags (global)
    _Float16* __restrict__ proj,          // [N][64] fp16
    const int* __restrict__ gid,          // [N]
    int* __restrict__ cursor,             // [G]
    int* __restrict__ bucket)             // [N]
{
    if (blockIdx.x < 512) {
        const int i = blockIdx.x * 256 + threadIdx.x;
        const int p = atomicAdd(&cursor[gid[i]], 1);
        bucket[p] = i;
        return;
    }

    __shared__ _Float16 WfL[16384];       // 32 KB B-frags
    {
        const int t = threadIdx.x;
        const float4* __restrict__ src = reinterpret_cast<const float4*>(Wf);
        float4* dst = reinterpret_cast<float4*>(WfL);
#pragma unroll
        for (int q = 0; q < 8; ++q)
            dst[t + 256 * q] = src[t + 256 * q];
    }
    __syncthreads();

    const int blk = blockIdx.x - 512;
    const int l = threadIdx.x & 63;
    const int w = threadIdx.x >> 6;
    const int rowbase = blk * 64 + w * 16;
    const int am = l & 15;                // A-frag row within tile
    const int q  = l >> 4;                // quad 0..3

    const float* __restrict__ arow = A + (size_t)(rowbase + am) * Dd + q * 8;
    const half8* __restrict__ bfrag = reinterpret_cast<const half8*>(WfL) + l;

    floatx4 acc[4];
#pragma unroll
    for (int t = 0; t < 4; ++t) acc[t] = (floatx4){0.f, 0.f, 0.f, 0.f};

#pragma unroll
    for (int c = 0; c < 8; ++c) {
        const float4 fa = *reinterpret_cast<const float4*>(arow + c * 32);
        const float4 fb = *reinterpret_cast<const float4*>(arow + c * 32 + 4);
        half8 a;
        a[0] = (_Float16)fa.x; a[1] = (_Float16)fa.y;
        a[2] = (_Float16)fa.z; a[3] = (_Float16)fa.w;
        a[4] = (_Float16)fb.x; a[5] = (_Float16)fb.y;
        a[6] = (_Float16)fb.z; a[7] = (_Float16)fb.w;
        const half8 b0 = bfrag[(c * 4 + 0) * 64];
        const half8 b1 = bfrag[(c * 4 + 1) * 64];
        const half8 b2 = bfrag[(c * 4 + 2) * 64];
        const half8 b3 = bfrag[(c * 4 + 3) * 64];
        acc[0] = __builtin_amdgcn_mfma_f32_16x16x32_f16(a, b0, acc[0], 0, 0, 0);
        acc[1] = __builtin_amdgcn_mfma_f32_16x16x32_f16(a, b1, acc[1], 0, 0, 0);
        acc[2] = __builtin_amdgcn_mfma_f32_16x16x32_f16(a, b2, acc[2], 0, 0, 0);
        acc[3] = __builtin_amdgcn_mfma_f32_16x16x32_f16(a, b3, acc[3], 0, 0, 0);
    }

    // C/D layout: col = l&15, row = q*4 + reg  (m89-verified mapping)
#pragma unroll
    for (int t = 0; t < 4; ++t) {
#pragma unroll
        for (int r = 0; r < 4; ++r) {
            proj[(size_t)(rowbase + q * 4 + r) * Pp + t * 16 + am] =
                (_Float16)acc[t][r];
        }
    }
}

// ---------------------------------------------------------------------------
// K3 (merged): blocks [0,2048): group means (one wave per group, lane =
// float4 column slice, 16-deep unrolled gathers — avg group (n=16) issues
// all its row loads in one flight); blocks [2048, +2032): edge logits over
// fp16 proj (8 lanes/edge, 4 edges/subgroup, 3-step shuffle reduce).
// ---------------------------------------------------------------------------
__global__ __launch_bounds__(256) void k_tail(
    const float* __restrict__ features,   // [N][256]
    const int* __restrict__ bucket,       // [N]
    const int* __restrict__ offsets,      // [G]
    const int* __restrict__ cnt,          // [G]
    float* __restrict__ out_means,        // [G][256]
    const _Float16* __restrict__ proj,    // [N][64] fp16
    const int* __restrict__ ei,           // [2][E]
    float* __restrict__ out_logits)       // [E]
{
    if (blockIdx.x < 2048) {
        const int lane = threadIdx.x & 63;
        const int g = blockIdx.x * 4 + (threadIdx.x >> 6);
        const int n = cnt[g];
        const int start = offsets[g];
        const int col = lane * 4;
        const int* __restrict__ bk = bucket + start;

        float4 s = make_float4(0.f, 0.f, 0.f, 0.f);
        int k = 0;
        for (; k + 16 <= n; k += 16) {
            int r[16];
#pragma unroll
            for (int u = 0; u < 16; ++u) r[u] = bk[k + u];
            float4 f[16];
#pragma unroll
            for (int u = 0; u < 16; ++u)
                f[u] = *reinterpret_cast<const float4*>(features + (size_t)r[u] * Dd + col);
#pragma unroll
            for (int u = 0; u < 16; ++u) {
                s.x += f[u].x; s.y += f[u].y; s.z += f[u].z; s.w += f[u].w;
            }
        }
        for (; k + 4 <= n; k += 4) {
            int r[4];
#pragma unroll
            for (int u = 0; u < 4; ++u) r[u] = bk[k + u];
            float4 f[4];
#pragma unroll
            for (int u = 0; u < 4; ++u)
                f[u] = *reinterpret_cast<const float4*>(features + (size_t)r[u] * Dd + col);
#pragma unroll
            for (int u = 0; u < 4; ++u) {
                s.x += f[u].x; s.y += f[u].y; s.z += f[u].z; s.w += f[u].w;
            }
        }
        for (; k < n; ++k) {
            const float4 f = *reinterpret_cast<const float4*>(features + (size_t)bk[k] * Dd + col);
            s.x += f.x; s.y += f.y; s.z += f.z; s.w += f.w;
        }
        const float inv = 1.0f / (float)max(n, 1);
        s.x *= inv; s.y *= inv; s.z *= inv; s.w *= inv;
        *reinterpret_cast<float4*>(out_means + (size_t)g * Dd + col) = s;
        return;
    }

    const int bid = blockIdx.x - 2048;
    const int sub = threadIdx.x & 7;                   // lane within edge
    const int sg  = bid * 32 + (threadIdx.x >> 3);     // subgroup id
    const int e0  = sg * 4;

    int s[4], t[4];
#pragma unroll
    for (int u = 0; u < 4; ++u) { s[u] = ei[e0 + u]; t[u] = ei[Ee + e0 + u]; }

    half8 a[4], b[4];
#pragma unroll
    for (int u = 0; u < 4; ++u) {
        a[u] = *reinterpret_cast<const half8*>(proj + (size_t)s[u] * Pp + sub * 8);
        b[u] = *reinterpret_cast<const half8*>(proj + (size_t)t[u] * Pp + sub * 8);
    }

    float v[4];
#pragma unroll
    for (int u = 0; u < 4; ++u) {
        float acc = 0.f;
#pragma unroll
        for (int j = 0; j < 8; ++j)
            acc = fmaf((float)a[u][j], (float)b[u][j], acc);
        v[u] = acc;
    }

#pragma unroll
    for (int off = 4; off >= 1; off >>= 1) {
#pragma unroll
        for (int u = 0; u < 4; ++u) v[u] += __shfl_xor(v[u], off, 64);
    }

    if (sub < 4) {
        const float x = v[sub];
        out_logits[e0 + sub] = 1.0f / (1.0f + __expf(-(x - SIM_TH)));
    }
}

// ---------------------------------------------------------------------------
extern "C" void kernel_launch(void* const* d_in, const int* in_sizes, int n_in,
                              void* d_out, int out_size, void* d_ws, size_t ws_size,
                              hipStream_t stream)
{
    const float* features = (const float*)d_in[0];
    const float* W        = (const float*)d_in[1];
    const int*   ei       = (const int*)d_in[2];
    const int*   gid      = (const int*)d_in[3];
    // d_in[4] = num_groups scalar (fixed at 8192, hardcoded)

    float* out_means  = (float*)d_out;                    // [G*D]
    float* out_logits = out_means + (size_t)Gg * Dd;      // [E]

    _Float16*  proj    = (_Float16*)d_ws;                 // N*P f16 (16 MB)
    int*       bucket  = (int*)(proj + (size_t)Nn * Pp);  // [N]
    int*       cnt     = bucket + Nn;                     // [G]
    int*       offsets = cnt + Gg;                        // [G]
    int*       cursor  = offsets + Gg;                    // [G]
    _Float16*  Wf      = (_Float16*)(cursor + Gg);        // 16384 f16 (32 KB)

    hipMemsetAsync(cnt, 0, (size_t)Gg * sizeof(int), stream);

    hipLaunchKernelGGL(k_count_wfrag, dim3(Nn / 256), dim3(256), 0, stream,
                       gid, cnt, W, Wf);
    hipLaunchKernelGGL(k_scan, dim3(1), dim3(256), 0, stream,
                       cnt, offsets, cursor);
    hipLaunchKernelGGL(k_mid, dim3(512 + Nn / 64), dim3(256), 0, stream,
                       features, Wf, proj, gid, cursor, bucket);
    hipLaunchKernelGGL(k_tail, dim3(2048 + Ee / 128), dim3(256), 0, stream,
                       features, bucket, offsets, cnt, out_means,
                       proj, ei, out_logits);
}